// Round 2
// baseline (747.017 us; speedup 1.0000x reference)
//
#include <hip/hip_runtime.h>

typedef __attribute__((ext_vector_type(4))) float f32x4;
typedef __attribute__((ext_vector_type(8))) short s16x8;
typedef unsigned short u16;

#define KGEN 32
#define NTAPS 28

__device__ __forceinline__ float bf2f(u16 v) {
    return __uint_as_float(((unsigned)v) << 16);
}
__device__ __forceinline__ u16 f2bf(float f) {
    unsigned u = __float_as_uint(f);
    unsigned r = (u + 0x7fffu + ((u >> 16) & 1u)) >> 16;
    return (u16)r;
}

// async 16B global -> LDS (wave-uniform LDS base + lane*16 pattern)
#define ASYNC_COPY16(gptr, lptr)                                               \
    __builtin_amdgcn_global_load_lds(                                          \
        (const __attribute__((address_space(1))) unsigned int*)(gptr),         \
        (__attribute__((address_space(3))) unsigned int*)(lptr), 16, 0, 0)

// ---------------------------------------------------------------------------
// PREP: blockIdx 0..1 = gen (hz/vt taps), 2..513 = fold (Wcat), rest = fromrgb.
// hzvt layout: [2][256][3] fp32.  wcat: [512][512] bf16.  xu: [pos][512] bf16
// with x at channels 256..511.
// ---------------------------------------------------------------------------
__global__ __launch_bounds__(256) void prep_kernel(
    const float* __restrict__ freqs, const float* __restrict__ phases,
    const float* __restrict__ hz_outdim, const float* __restrict__ vt_outdim,
    const float* __restrict__ gsig, const float* __restrict__ low_filter,
    const float* __restrict__ gauss_x, float* __restrict__ hzvt,
    const float* __restrict__ point_w, const float* __restrict__ lr_w,
    u16* __restrict__ wcat,
    const float* __restrict__ img, const float* __restrict__ frw,
    const float* __restrict__ frb, u16* __restrict__ xu)
{
    __shared__ union {
        struct {
            float basis[256][KGEN];
            float red[256];
            float colscale[KGEN];
        } g;
        float pw[256];
    } sm;

    const int bidx = blockIdx.x;
    const int t = threadIdx.x;

    if (bidx < 2) {
        // ---------------- gen ----------------
        const int which = bidx;   // 0 = hz (freqs[:,0]), 1 = vt
        const int i = t;          // row 0..255
        {
            float f = freqs[i * 2 + which];
            float p = phases[i];
            #pragma unroll
            for (int j = 0; j < KGEN; j++) {
                float g = ((float)j - 15.5f) * (2.0f / 33.0f);
                sm.g.basis[i][j] = sinf((f * g + p) * 6.283185307179586f) * 0.6065306597126334f;
            }
        }
        __syncthreads();

        const float* coeff = (which == 0) ? hz_outdim : vt_outdim;
        float acc[KGEN];
        #pragma unroll
        for (int j = 0; j < KGEN; j++) acc[j] = 0.f;

        const float4* crow = (const float4*)(coeff + (size_t)i * 256);
        for (int c4 = 0; c4 < 64; c4++) {
            float4 cv = crow[c4];
            int c = c4 * 4;
            #pragma unroll
            for (int j = 0; j < KGEN; j++) {
                acc[j] += sm.g.basis[c][j] * cv.x + sm.g.basis[c + 1][j] * cv.y
                        + sm.g.basis[c + 2][j] * cv.z + sm.g.basis[c + 3][j] * cv.w;
            }
        }
        #pragma unroll
        for (int j = 0; j < KGEN; j++) acc[j] *= 0.0625f;  // 1/sqrt(256)

        float s = 0.f;
        #pragma unroll
        for (int j = 0; j < KGEN; j++) s += acc[j];
        sm.g.red[i] = s;
        __syncthreads();
        for (int st = 128; st > 0; st >>= 1) {
            if (i < st) sm.g.red[i] += sm.g.red[i + st];
            __syncthreads();
        }
        float mean = sm.g.red[0] * (1.0f / 8192.0f);
        #pragma unroll
        for (int j = 0; j < KGEN; j++) acc[j] -= mean;

        #pragma unroll
        for (int j = 0; j < KGEN; j++) sm.g.basis[i][j] = acc[j];
        __syncthreads();
        if (i < KGEN) {
            float ss = 0.f;
            for (int r = 0; r < 256; r++) { float v = sm.g.basis[r][i]; ss += v * v; }
            sm.g.colscale[i] = rsqrtf(ss * (1.0f / 256.0f) + 1e-8f);
        }
        __syncthreads();

        float sg = gsig[0];
        float gs = 1.0f + sg * sg * 0.2f;
        #pragma unroll
        for (int j = 0; j < KGEN; j++) {
            float gx = gauss_x[j];
            acc[j] = acc[j] * sm.g.colscale[j] * expf(-(gx * gx) / (2.0f * gs));
        }

        float lf[NTAPS];
        #pragma unroll
        for (int tt = 0; tt < NTAPS; tt++) lf[tt] = low_filter[tt];
        #pragma unroll
        for (int p = 0; p < 3; p++) {
            int t0 = 2 * p;
            float o = 0.f;
            #pragma unroll
            for (int tt = 0; tt < NTAPS; tt++) o += acc[t0 + tt] * lf[tt];
            hzvt[((size_t)which * 256 + i) * 3 + p] = o;
        }
    } else if (bidx < 514) {
        // ---------------- fold ----------------
        const int n = bidx - 2;
        const int j = t;
        sm.pw[j] = point_w[(size_t)n * 256 + j];
        __syncthreads();
        float a0 = 0.f, a1 = 0.f, a2 = 0.f, a3 = 0.f;
        for (int c = 0; c < 256; c += 4) {
            a0 += sm.pw[c + 0] * lr_w[(size_t)(c + 0) * 256 + j];
            a1 += sm.pw[c + 1] * lr_w[(size_t)(c + 1) * 256 + j];
            a2 += sm.pw[c + 2] * lr_w[(size_t)(c + 2) * 256 + j];
            a3 += sm.pw[c + 3] * lr_w[(size_t)(c + 3) * 256 + j];
        }
        float acc = (a0 + a1) + (a2 + a3);
        wcat[(size_t)n * 512 + j]       = f2bf(sm.pw[j] * 0.0625f);
        wcat[(size_t)n * 512 + 256 + j] = f2bf(acc * (1.0f / 256.0f));
    } else {
        // ---------------- fromrgb ----------------
        const int pos = (bidx - 514) * 8 + (t >> 5);
        const int c0 = (t & 31) * 8;
        const int b = pos >> 14;
        const int hw = pos & 16383;

        const float* ib = img + (size_t)b * 3 * 16384 + hw;
        float s0 = sinf(ib[0]);
        float s1 = sinf(ib[16384]);
        float s2 = sinf(ib[32768]);
        const float g = 0.5773502691896258f;  // 1/sqrt(3)

        union { float4 v[6]; float f[24]; } wv;
        const float4* wp = (const float4*)(frw + (size_t)c0 * 3);
        #pragma unroll
        for (int q = 0; q < 6; q++) wv.v[q] = wp[q];

        union { u16 q[8]; s16x8 v; } ov;
        #pragma unroll
        for (int q = 0; q < 8; q++) {
            float v = (s0 * wv.f[q * 3 + 0] + s1 * wv.f[q * 3 + 1] + s2 * wv.f[q * 3 + 2]) * g
                    + frb[c0 + q];
            v = fminf(256.f, fmaxf(-256.f, v));
            ov.q[q] = f2bf(v);
        }
        *(s16x8*)(xu + (size_t)pos * 512 + 256 + c0) = ov.v;
    }
}

// ---------------------------------------------------------------------------
// K3: depthwise 3x3 (vt outer hz), gain 1/3. Reads x (ch 256..511 of xu),
// writes u into ch 0..255 of xu. One thread = one pos x 8 channels.
// ---------------------------------------------------------------------------
__global__ __launch_bounds__(256) void dw_kernel(
    u16* __restrict__ xu, const float* __restrict__ hzvt)
{
    const int t = blockIdx.x * 256 + threadIdx.x;
    const int c0 = (t & 31) * 8;
    const int pos = t >> 5;
    const int w = pos & 127;
    const int h = (pos >> 7) & 127;
    const int b = pos >> 14;

    union { float4 v[6]; float f[24]; } hzw, vtw;
    const float4* hp = (const float4*)(hzvt + (size_t)c0 * 3);
    const float4* vp = (const float4*)(hzvt + 768 + (size_t)c0 * 3);
    #pragma unroll
    for (int q = 0; q < 6; q++) { hzw.v[q] = hp[q]; vtw.v[q] = vp[q]; }

    float acc8[8];
    #pragma unroll
    for (int q = 0; q < 8; q++) acc8[q] = 0.f;

    #pragma unroll
    for (int i = 0; i < 3; i++) {
        int hh = h + i - 1;
        if (hh < 0 || hh > 127) continue;
        float hr[8];
        #pragma unroll
        for (int q = 0; q < 8; q++) hr[q] = 0.f;
        #pragma unroll
        for (int j = 0; j < 3; j++) {
            int ww = w + j - 1;
            if (ww < 0 || ww > 127) continue;
            const u16* xp = xu + ((size_t)((b * 128 + hh) * 128 + ww) * 512 + 256 + c0);
            s16x8 xv = *(const s16x8*)xp;
            #pragma unroll
            for (int q = 0; q < 8; q++) hr[q] += hzw.f[q * 3 + j] * bf2f((u16)xv[q]);
        }
        #pragma unroll
        for (int q = 0; q < 8; q++) acc8[q] += vtw.f[q * 3 + i] * hr[q];
    }

    union { u16 q[8]; s16x8 v; } ov;
    #pragma unroll
    for (int q = 0; q < 8; q++) ov.q[q] = f2bf(acc8[q] * (1.0f / 3.0f));
    *(s16x8*)(xu + (size_t)pos * 512 + c0) = ov.v;
}

// ---------------------------------------------------------------------------
// K4: GEMM ypre[m][n] = lrelu(sum_k A[m][k]*Wcat[n][k] + bias)
// A = xu (NHWC, K=512), B^T = wcat.  128x128 tile, BK=64, 8 k-iters, 4 waves.
// XOR chunk swizzle: k-chunk c (16B) of row r lives at LDS slot c^(r&7) so
// the frag ds_read_b128 pattern covers all 32 banks (2-way only).
// Writes ypre in NCHW-half layout [B][256][128][128] bf16 for the FIR pass.
// ---------------------------------------------------------------------------
__global__ __launch_bounds__(256) void gemm_kernel(
    const u16* __restrict__ xu, const u16* __restrict__ wcat,
    const float* __restrict__ point_b, u16* __restrict__ ypre, int nofs)
{
    __shared__ u16 As[128 * 64];  // 16 KB, [row][slot*8], slot xor-swizzled
    __shared__ u16 Bs[128 * 64];

    const int tid = threadIdx.x;
    const int bid = blockIdx.x;
    // XCD swizzle: the 2 n-tiles sharing an A-tile land 8 apart (same XCD)
    const int ntile = (bid >> 3) & 1;
    const int mtile = (bid & 7) | ((bid >> 4) << 3);

    // staging: thread -> (row = tid>>3 (+32 per instr), slot = tid&7)
    const int srow = tid >> 3;            // 0..31
    const int slot = tid & 7;             // 16B slot within the 64-elem row
    const int ek = slot ^ (srow & 7);     // which global k-chunk fills it
    const size_t abase = (size_t)(mtile * 128 + srow) * 512 + ek * 8;
    const int nbase = nofs + ntile * 128;
    const size_t bbase = (size_t)(nbase + srow) * 512 + ek * 8;
    u16* asdst = &As[(size_t)tid * 8];
    u16* bsdst = &Bs[(size_t)tid * 8];

    const int lane = tid & 63;
    const int wave = tid >> 6;
    const int wm = (wave >> 1) * 64;
    const int wn = (wave & 1) * 64;
    const int l16 = lane & 15;
    const int lq = lane >> 4;

    f32x4 acc[4][4];
    #pragma unroll
    for (int a = 0; a < 4; a++)
        #pragma unroll
        for (int c = 0; c < 4; c++) acc[a][c] = (f32x4){0.f, 0.f, 0.f, 0.f};

    for (int kt = 0; kt < 8; kt++) {
        __syncthreads();
        const int ko = kt * 64;
        #pragma unroll
        for (int i = 0; i < 4; i++) {
            ASYNC_COPY16(xu + abase + (size_t)i * 32 * 512 + ko, asdst + i * 2048);
            ASYNC_COPY16(wcat + bbase + (size_t)i * 32 * 512 + ko, bsdst + i * 2048);
        }
        __syncthreads();

        #pragma unroll
        for (int kk = 0; kk < 2; kk++) {
            s16x8 af[4], bf[4];
            #pragma unroll
            for (int mi = 0; mi < 4; mi++) {
                const int r = wm + mi * 16 + l16;
                af[mi] = *(const s16x8*)&As[r * 64 + (((kk * 4 + lq) ^ (r & 7)) * 8)];
            }
            #pragma unroll
            for (int ni = 0; ni < 4; ni++) {
                const int r = wn + ni * 16 + l16;
                bf[ni] = *(const s16x8*)&Bs[r * 64 + (((kk * 4 + lq) ^ (r & 7)) * 8)];
            }
            #pragma unroll
            for (int mi = 0; mi < 4; mi++)
                #pragma unroll
                for (int ni = 0; ni < 4; ni++)
                    acc[mi][ni] = __builtin_amdgcn_mfma_f32_16x16x32_bf16(
                        af[mi], bf[ni], acc[mi][ni], 0, 0, 0);
        }
    }

    // epilogue: bias + lrelu*sqrt(2) + clamp, store NCHW bf16 (4 w per store)
    const int b = mtile >> 7;
    const int h = mtile & 127;
    #pragma unroll
    for (int ni = 0; ni < 4; ni++) {
        const int nl = ntile * 128 + wn + ni * 16 + l16;  // local n in [0,256)
        const float bias = point_b[nofs + nl];
        u16* drow = ypre + ((size_t)(b * 256 + nl) * 128 + h) * 128;
        #pragma unroll
        for (int mi = 0; mi < 4; mi++) {
            const int w0 = wm + mi * 16 + lq * 4;
            union { u16 q[4]; uint2 d; } pk;
            #pragma unroll
            for (int r = 0; r < 4; r++) {
                float v = acc[mi][ni][r] + bias;
                v = (v >= 0.f) ? v : 0.2f * v;
                v *= 1.4142135623730951f;
                v = fminf(256.f, fmaxf(-256.f, v));
                pk.q[r] = f2bf(v);
            }
            *(uint2*)(drow + w0) = pk.d;
        }
    }
}

// ---------------------------------------------------------------------------
// K5: FIR downsample 2x with separable [1,3,3,1]/8, pad 1.
// One block per (b, n-local), 4 waves; wave w owns output rows w*16..w*16+15.
// lane = ow; ring over oh (2 new rows per oh).
// ---------------------------------------------------------------------------
__global__ __launch_bounds__(256) void fir_kernel(
    const u16* __restrict__ ypre, const float* __restrict__ fir,
    float* __restrict__ out, int nofs)
{
    const int bid = blockIdx.x;
    const int tid = threadIdx.x;
    const int lane = tid & 63;     // ow 0..63
    const int wave = tid >> 6;     // oh block
    const int nl = bid & 255;
    const int b = bid >> 8;
    const u16* src = ypre + (size_t)(b * 256 + nl) * 16384;
    float* dst = out + (size_t)(b * 512 + nofs + nl) * 4096;

    const float f0 = fir[0], f1 = fir[1], f2 = fir[2], f3 = fir[3];

    auto hrow = [&](int r) -> float {
        if (r < 0 || r > 127) return 0.f;
        unsigned raw = *(const unsigned*)(src + (size_t)r * 128 + lane * 2);
        float y0 = bf2f((u16)(raw & 0xffffu));
        float y1 = bf2f((u16)(raw >> 16));
        float ym = __shfl_up(y1, 1u);   // lane l-1's y1 = value at w=2l-1
        if (lane == 0) ym = 0.f;        // w = -1 pad
        float yp = __shfl_down(y0, 1u); // lane l+1's y0 = value at w=2l+2
        if (lane == 63) yp = 0.f;       // w = 128 pad
        return f0 * ym + f1 * y0 + f2 * y1 + f3 * yp;
    };

    const int oh0 = wave * 16;
    float A = hrow(2 * oh0 - 1);
    float Bv = hrow(2 * oh0);
    for (int oh = oh0; oh < oh0 + 16; oh++) {
        float C = hrow(2 * oh + 1);
        float D = hrow(2 * oh + 2);
        dst[oh * 64 + lane] = f0 * A + f1 * Bv + f2 * C + f3 * D;
        A = C;
        Bv = D;
    }
}

// ---------------------------------------------------------------------------
extern "C" void kernel_launch(void* const* d_in, const int* in_sizes, int n_in,
                              void* d_out, int out_size, void* d_ws, size_t ws_size,
                              hipStream_t stream)
{
    (void)in_sizes; (void)n_in; (void)out_size; (void)ws_size;
    const float* img        = (const float*)d_in[0];
    const float* fromrgb_w  = (const float*)d_in[1];
    const float* fromrgb_b  = (const float*)d_in[2];
    const float* freqs      = (const float*)d_in[3];
    const float* phases     = (const float*)d_in[4];
    const float* hz_outdim  = (const float*)d_in[5];
    const float* vt_outdim  = (const float*)d_in[6];
    const float* gsig       = (const float*)d_in[7];
    const float* lr_w       = (const float*)d_in[8];
    const float* point_w    = (const float*)d_in[9];
    const float* point_b    = (const float*)d_in[10];
    const float* low_filter = (const float*)d_in[11];
    const float* gauss_x    = (const float*)d_in[12];
    const float* fir        = (const float*)d_in[13];

    char* ws = (char*)d_ws;
    u16*   xu   = (u16*)(ws);                      // 262144*512*2  = 256 MiB
    u16*   ypre = (u16*)(ws + 268435456LL);        // 16*256*128*128*2 = 128 MiB
    u16*   wcat = (u16*)(ws + 402653184LL);        // 512*512*2 = 512 KiB
    float* hzvt = (float*)(ws + 403177472LL);      // 2*256*3*4 = 6 KiB
    float* out  = (float*)d_out;

    hipLaunchKernelGGL(prep_kernel, dim3(33282), dim3(256), 0, stream,
                       freqs, phases, hz_outdim, vt_outdim, gsig, low_filter, gauss_x, hzvt,
                       point_w, lr_w, wcat, img, fromrgb_w, fromrgb_b, xu);
    hipLaunchKernelGGL(dw_kernel, dim3(32768), dim3(256), 0, stream,
                       xu, hzvt);
    for (int half = 0; half < 2; half++) {
        hipLaunchKernelGGL(gemm_kernel, dim3(4096), dim3(256), 0, stream,
                           xu, wcat, point_b, ypre, half * 256);
        hipLaunchKernelGGL(fir_kernel, dim3(4096), dim3(256), 0, stream,
                           ypre, fir, out, half * 256);
    }
}

// Round 3
// 677.836 us; speedup vs baseline: 1.1021x; 1.1021x over previous
//
#include <hip/hip_runtime.h>

typedef __attribute__((ext_vector_type(4))) float f32x4;
typedef __attribute__((ext_vector_type(8))) short s16x8;
typedef unsigned short u16;

#define KGEN 32
#define NTAPS 28

__device__ __forceinline__ float bf2f(u16 v) {
    return __uint_as_float(((unsigned)v) << 16);
}
__device__ __forceinline__ u16 f2bf(float f) {
    unsigned u = __float_as_uint(f);
    unsigned r = (u + 0x7fffu + ((u >> 16) & 1u)) >> 16;
    return (u16)r;
}

// async 16B global -> LDS (wave-uniform LDS base + lane*16 pattern)
#define ASYNC_COPY16(gptr, lptr)                                               \
    __builtin_amdgcn_global_load_lds(                                          \
        (const __attribute__((address_space(1))) unsigned int*)(gptr),         \
        (__attribute__((address_space(3))) unsigned int*)(lptr), 16, 0, 0)

// ---------------------------------------------------------------------------
// PREP: blockIdx 0..1 = gen (hz/vt taps), 2..513 = fold (Wcat), rest = fromrgb.
// hzvt layout: [2][256][3] fp32.  wcat: [512][512] bf16.  xu: [pos][512] bf16
// with x at channels 256..511.
// fromrgb: 32 positions/block; sins deduped via LDS (1 __sinf per pos*ch).
// ---------------------------------------------------------------------------
__global__ __launch_bounds__(256) void prep_kernel(
    const float* __restrict__ freqs, const float* __restrict__ phases,
    const float* __restrict__ hz_outdim, const float* __restrict__ vt_outdim,
    const float* __restrict__ gsig, const float* __restrict__ low_filter,
    const float* __restrict__ gauss_x, float* __restrict__ hzvt,
    const float* __restrict__ point_w, const float* __restrict__ lr_w,
    u16* __restrict__ wcat,
    const float* __restrict__ img, const float* __restrict__ frw,
    const float* __restrict__ frb, u16* __restrict__ xu)
{
    __shared__ union {
        struct {
            float basis[256][KGEN];
            float red[256];
            float colscale[KGEN];
        } g;
        float pw[256];
        struct {
            float sins[3][32];
            float wT[3][264];   // padded: index c + (c>>5) breaks 32-stride banks
            float bT[264];
        } f;
    } sm;

    const int bidx = blockIdx.x;
    const int t = threadIdx.x;

    if (bidx < 2) {
        // ---------------- gen ----------------
        const int which = bidx;   // 0 = hz (freqs[:,0]), 1 = vt
        const int i = t;          // row 0..255
        {
            float f = freqs[i * 2 + which];
            float p = phases[i];
            #pragma unroll
            for (int j = 0; j < KGEN; j++) {
                float g = ((float)j - 15.5f) * (2.0f / 33.0f);
                sm.g.basis[i][j] = __sinf((f * g + p) * 6.283185307179586f) * 0.6065306597126334f;
            }
        }
        __syncthreads();

        const float* coeff = (which == 0) ? hz_outdim : vt_outdim;
        float acc[KGEN];
        #pragma unroll
        for (int j = 0; j < KGEN; j++) acc[j] = 0.f;

        const float4* crow = (const float4*)(coeff + (size_t)i * 256);
        for (int c4 = 0; c4 < 64; c4++) {
            float4 cv = crow[c4];
            int c = c4 * 4;
            #pragma unroll
            for (int j = 0; j < KGEN; j++) {
                acc[j] += sm.g.basis[c][j] * cv.x + sm.g.basis[c + 1][j] * cv.y
                        + sm.g.basis[c + 2][j] * cv.z + sm.g.basis[c + 3][j] * cv.w;
            }
        }
        #pragma unroll
        for (int j = 0; j < KGEN; j++) acc[j] *= 0.0625f;  // 1/sqrt(256)

        float s = 0.f;
        #pragma unroll
        for (int j = 0; j < KGEN; j++) s += acc[j];
        sm.g.red[i] = s;
        __syncthreads();
        for (int st = 128; st > 0; st >>= 1) {
            if (i < st) sm.g.red[i] += sm.g.red[i + st];
            __syncthreads();
        }
        float mean = sm.g.red[0] * (1.0f / 8192.0f);
        #pragma unroll
        for (int j = 0; j < KGEN; j++) acc[j] -= mean;

        #pragma unroll
        for (int j = 0; j < KGEN; j++) sm.g.basis[i][j] = acc[j];
        __syncthreads();
        if (i < KGEN) {
            float ss = 0.f;
            for (int r = 0; r < 256; r++) { float v = sm.g.basis[r][i]; ss += v * v; }
            sm.g.colscale[i] = rsqrtf(ss * (1.0f / 256.0f) + 1e-8f);
        }
        __syncthreads();

        float sg = gsig[0];
        float gs = 1.0f + sg * sg * 0.2f;
        #pragma unroll
        for (int j = 0; j < KGEN; j++) {
            float gx = gauss_x[j];
            acc[j] = acc[j] * sm.g.colscale[j] * expf(-(gx * gx) / (2.0f * gs));
        }

        float lf[NTAPS];
        #pragma unroll
        for (int tt = 0; tt < NTAPS; tt++) lf[tt] = low_filter[tt];
        #pragma unroll
        for (int p = 0; p < 3; p++) {
            int t0 = 2 * p;
            float o = 0.f;
            #pragma unroll
            for (int tt = 0; tt < NTAPS; tt++) o += acc[t0 + tt] * lf[tt];
            hzvt[((size_t)which * 256 + i) * 3 + p] = o;
        }
    } else if (bidx < 514) {
        // ---------------- fold ----------------
        const int n = bidx - 2;
        const int j = t;
        sm.pw[j] = point_w[(size_t)n * 256 + j];
        __syncthreads();
        float a0 = 0.f, a1 = 0.f, a2 = 0.f, a3 = 0.f;
        for (int c = 0; c < 256; c += 4) {
            a0 += sm.pw[c + 0] * lr_w[(size_t)(c + 0) * 256 + j];
            a1 += sm.pw[c + 1] * lr_w[(size_t)(c + 1) * 256 + j];
            a2 += sm.pw[c + 2] * lr_w[(size_t)(c + 2) * 256 + j];
            a3 += sm.pw[c + 3] * lr_w[(size_t)(c + 3) * 256 + j];
        }
        float acc = (a0 + a1) + (a2 + a3);
        wcat[(size_t)n * 512 + j]       = f2bf(sm.pw[j] * 0.0625f);
        wcat[(size_t)n * 512 + 256 + j] = f2bf(acc * (1.0f / 256.0f));
    } else {
        // ---------------- fromrgb ----------------
        const int pos_base = (bidx - 514) * 32;
        const int b = pos_base >> 14;
        const int hw = pos_base & 16383;

        // stage sins (once per pos,ch), weights (padded transpose), bias
        if (t < 96) {
            const int ch = t >> 5, p = t & 31;
            sm.f.sins[ch][p] = __sinf(img[((size_t)b * 3 + ch) * 16384 + hw + p]);
        }
        for (int idx = t; idx < 768; idx += 256) {
            const int c = idx / 3, k = idx - c * 3;
            sm.f.wT[k][c + (c >> 5)] = frw[idx];
        }
        sm.f.bT[t + (t >> 5)] = frb[t];
        __syncthreads();

        const int p = t >> 3;            // position 0..31
        const int g8 = t & 7;            // channel group
        const int c0 = g8 * 32;
        const float s0 = sm.f.sins[0][p];
        const float s1 = sm.f.sins[1][p];
        const float s2 = sm.f.sins[2][p];
        const float gn = 0.5773502691896258f;  // 1/sqrt(3)

        u16* dst = xu + (size_t)(pos_base + p) * 512 + 256 + c0;
        #pragma unroll
        for (int q0 = 0; q0 < 4; q0++) {
            union { u16 q[8]; s16x8 v; } ov;
            #pragma unroll
            for (int q = 0; q < 8; q++) {
                const int cp = c0 + q0 * 8 + q + g8;   // padded index
                float v = (s0 * sm.f.wT[0][cp] + s1 * sm.f.wT[1][cp]
                         + s2 * sm.f.wT[2][cp]) * gn + sm.f.bT[cp];
                v = fminf(256.f, fmaxf(-256.f, v));
                ov.q[q] = f2bf(v);
            }
            *(s16x8*)(dst + q0 * 8) = ov.v;
        }
    }
}

// ---------------------------------------------------------------------------
// K3: depthwise 3x3 (vt outer hz), gain 1/3. Reads x (ch 256..511 of xu),
// writes u into ch 0..255 of xu. One thread = 4 positions x 8 channels
// (column reuse: 18 loads instead of 36).
// ---------------------------------------------------------------------------
__global__ __launch_bounds__(256) void dw_kernel(
    u16* __restrict__ xu, const float* __restrict__ hzvt)
{
    const int t = threadIdx.x;
    const int c0 = (t & 31) * 8;
    const int wq = t >> 5;                       // 0..7
    const int pos0 = blockIdx.x * 32 + wq * 4;   // 4 consecutive w
    const int w0 = pos0 & 127;
    const int h = (pos0 >> 7) & 127;
    const int b = pos0 >> 14;

    union { float4 v[6]; float f[24]; } hzw, vtw;
    const float4* hp = (const float4*)(hzvt + (size_t)c0 * 3);
    const float4* vp = (const float4*)(hzvt + 768 + (size_t)c0 * 3);
    #pragma unroll
    for (int q = 0; q < 6; q++) { hzw.v[q] = hp[q]; vtw.v[q] = vp[q]; }

    float acc[4][8];
    #pragma unroll
    for (int o = 0; o < 4; o++)
        #pragma unroll
        for (int q = 0; q < 8; q++) acc[o][q] = 0.f;

    #pragma unroll
    for (int i = 0; i < 3; i++) {
        int hh = h + i - 1;
        if (hh < 0 || hh > 127) continue;
        // fused weights w2[j][q] = vt[i][q]*hz[j][q]
        float w2[3][8];
        #pragma unroll
        for (int q = 0; q < 8; q++) {
            const float vq = vtw.f[q * 3 + i];
            w2[0][q] = vq * hzw.f[q * 3 + 0];
            w2[1][q] = vq * hzw.f[q * 3 + 1];
            w2[2][q] = vq * hzw.f[q * 3 + 2];
        }
        const u16* rowp = xu + ((size_t)((b * 128 + hh) * 128) * 512) + 256 + c0;
        #pragma unroll
        for (int dx = 0; dx < 6; dx++) {
            const int ww = w0 + dx - 1;
            s16x8 xv;
            if (ww >= 0 && ww <= 127) xv = *(const s16x8*)(rowp + (size_t)ww * 512);
            else xv = (s16x8){0,0,0,0,0,0,0,0};
            float xf[8];
            #pragma unroll
            for (int q = 0; q < 8; q++) xf[q] = bf2f((u16)xv[q]);
            // output o uses columns dx = o..o+2 with weight w2[dx-o]
            #pragma unroll
            for (int o = 0; o < 4; o++) {
                const int j = dx - o;
                if (j < 0 || j > 2) continue;
                #pragma unroll
                for (int q = 0; q < 8; q++) acc[o][q] += w2[j][q] * xf[q];
            }
        }
    }

    #pragma unroll
    for (int o = 0; o < 4; o++) {
        union { u16 q[8]; s16x8 v; } ov;
        #pragma unroll
        for (int q = 0; q < 8; q++) ov.q[q] = f2bf(acc[o][q] * (1.0f / 3.0f));
        *(s16x8*)(xu + (size_t)(pos0 + o) * 512 + c0) = ov.v;
    }
}

// ---------------------------------------------------------------------------
// K4: GEMM ypre[m][n] = lrelu(sum_k A[m][k]*Wcat[n][k] + bias)
// A = xu (NHWC, K=512), B^T = wcat.  128x128 tile, BK=64, 8 k-iters, 4 waves.
// XOR chunk swizzle on LDS (bank-conflict-free staging + frag reads).
// Epilogue: acc -> XOR-swizzled 32KB LDS transpose -> 256B-segment stores.
// ypre layout: [B][256][128][128] bf16 (NCHW halves).
// ---------------------------------------------------------------------------
__global__ __launch_bounds__(256) void gemm_kernel(
    const u16* __restrict__ xu, const u16* __restrict__ wcat,
    const float* __restrict__ point_b, u16* __restrict__ ypre, int nofs)
{
    __shared__ u16 smem[16384];   // stage: As[0..8191], Bs[8192..]; epi: all 32KB
    u16* As = smem;
    u16* Bs = smem + 8192;

    const int tid = threadIdx.x;
    const int bid = blockIdx.x;
    // XCD swizzle: the 2 n-tiles sharing an A-tile land 8 apart (same XCD)
    const int ntile = (bid >> 3) & 1;
    const int mtile = (bid & 7) | ((bid >> 4) << 3);

    // staging: thread -> (row = tid>>3 (+32 per instr), slot = tid&7)
    const int srow = tid >> 3;            // 0..31
    const int slot = tid & 7;             // 16B slot within the 64-elem row
    const int ek = slot ^ (srow & 7);     // which global k-chunk fills it
    const size_t abase = (size_t)(mtile * 128 + srow) * 512 + ek * 8;
    const int nbase = nofs + ntile * 128;
    const size_t bbase = (size_t)(nbase + srow) * 512 + ek * 8;
    u16* asdst = &As[(size_t)tid * 8];
    u16* bsdst = &Bs[(size_t)tid * 8];

    const int lane = tid & 63;
    const int wave = tid >> 6;
    const int wm = (wave >> 1) * 64;
    const int wn = (wave & 1) * 64;
    const int l16 = lane & 15;
    const int lq = lane >> 4;

    f32x4 acc[4][4];
    #pragma unroll
    for (int a = 0; a < 4; a++)
        #pragma unroll
        for (int c = 0; c < 4; c++) acc[a][c] = (f32x4){0.f, 0.f, 0.f, 0.f};

    for (int kt = 0; kt < 8; kt++) {
        __syncthreads();
        const int ko = kt * 64;
        #pragma unroll
        for (int i = 0; i < 4; i++) {
            ASYNC_COPY16(xu + abase + (size_t)i * 32 * 512 + ko, asdst + i * 2048);
            ASYNC_COPY16(wcat + bbase + (size_t)i * 32 * 512 + ko, bsdst + i * 2048);
        }
        __syncthreads();

        #pragma unroll
        for (int kk = 0; kk < 2; kk++) {
            s16x8 af[4], bf[4];
            #pragma unroll
            for (int mi = 0; mi < 4; mi++) {
                const int r = wm + mi * 16 + l16;
                af[mi] = *(const s16x8*)&As[r * 64 + (((kk * 4 + lq) ^ (r & 7)) * 8)];
            }
            #pragma unroll
            for (int ni = 0; ni < 4; ni++) {
                const int r = wn + ni * 16 + l16;
                bf[ni] = *(const s16x8*)&Bs[r * 64 + (((kk * 4 + lq) ^ (r & 7)) * 8)];
            }
            #pragma unroll
            for (int mi = 0; mi < 4; mi++)
                #pragma unroll
                for (int ni = 0; ni < 4; ni++)
                    acc[mi][ni] = __builtin_amdgcn_mfma_f32_16x16x32_bf16(
                        af[mi], bf[ni], acc[mi][ni], 0, 0, 0);
        }
    }

    // epilogue phase 1: activate, pack bf16, write to swizzled LDS [n][m-chunks]
    __syncthreads();
    #pragma unroll
    for (int ni = 0; ni < 4; ni++) {
        const int nloc = wn + ni * 16 + l16;              // 0..127 within tile
        const float bias = point_b[nofs + ntile * 128 + nloc];
        #pragma unroll
        for (int mi = 0; mi < 4; mi++) {
            const int m0 = wm + mi * 16 + lq * 4;
            union { u16 q[4]; uint2 d; } pk;
            #pragma unroll
            for (int r = 0; r < 4; r++) {
                float v = acc[mi][ni][r] + bias;
                v = (v >= 0.f) ? v : 0.2f * v;
                v *= 1.4142135623730951f;
                v = fminf(256.f, fmaxf(-256.f, v));
                pk.q[r] = f2bf(v);
            }
            const int chunk = m0 >> 3;
            const int within = m0 & 7;                    // 0 or 4
            const int sl = chunk ^ (nloc & 7);
            *(uint2*)&smem[nloc * 128 + sl * 8 + within] = pk.d;
        }
    }
    __syncthreads();

    // epilogue phase 2: contiguous 128B-per-thread stores (256B/row segments)
    const int b = mtile >> 7;
    const int h = mtile & 127;
    const int nl2 = tid >> 1;
    const int halfsel = tid & 1;
    const int nl = ntile * 128 + nl2;
    u16* drow = ypre + ((size_t)(b * 256 + nl) * 128 + h) * 128;
    #pragma unroll
    for (int j = 0; j < 8; j++) {
        const int c = halfsel * 8 + j;
        const int sl = c ^ (nl2 & 7);
        uint4 v = *(const uint4*)&smem[nl2 * 128 + sl * 8];
        *(uint4*)(drow + c * 8) = v;
    }
}

// ---------------------------------------------------------------------------
// K5: FIR downsample 2x with separable [1,3,3,1]/8, pad 1.
// 2 blocks per (b, n-local), 4 waves each; wave owns 8 output rows.
// lane = ow; ring over oh (2 new rows per oh).
// ---------------------------------------------------------------------------
__global__ __launch_bounds__(256) void fir_kernel(
    const u16* __restrict__ ypre, const float* __restrict__ fir,
    float* __restrict__ out, int nofs)
{
    const int bid = blockIdx.x;
    const int tid = threadIdx.x;
    const int lane = tid & 63;     // ow 0..63
    const int wave = tid >> 6;
    const int ohhalf = bid & 1;
    const int nl = (bid >> 1) & 255;
    const int b = bid >> 9;
    const u16* src = ypre + (size_t)(b * 256 + nl) * 16384;
    float* dst = out + (size_t)(b * 512 + nofs + nl) * 4096;

    const float f0 = fir[0], f1 = fir[1], f2 = fir[2], f3 = fir[3];

    auto hrow = [&](int r) -> float {
        if (r < 0 || r > 127) return 0.f;
        unsigned raw = *(const unsigned*)(src + (size_t)r * 128 + lane * 2);
        float y0 = bf2f((u16)(raw & 0xffffu));
        float y1 = bf2f((u16)(raw >> 16));
        float ym = __shfl_up(y1, 1u);   // lane l-1's y1 = value at w=2l-1
        if (lane == 0) ym = 0.f;        // w = -1 pad
        float yp = __shfl_down(y0, 1u); // lane l+1's y0 = value at w=2l+2
        if (lane == 63) yp = 0.f;       // w = 128 pad
        return f0 * ym + f1 * y0 + f2 * y1 + f3 * yp;
    };

    const int oh0 = ohhalf * 32 + wave * 8;
    float A = hrow(2 * oh0 - 1);
    float Bv = hrow(2 * oh0);
    for (int oh = oh0; oh < oh0 + 8; oh++) {
        float C = hrow(2 * oh + 1);
        float D = hrow(2 * oh + 2);
        dst[oh * 64 + lane] = f0 * A + f1 * Bv + f2 * C + f3 * D;
        A = C;
        Bv = D;
    }
}

// ---------------------------------------------------------------------------
extern "C" void kernel_launch(void* const* d_in, const int* in_sizes, int n_in,
                              void* d_out, int out_size, void* d_ws, size_t ws_size,
                              hipStream_t stream)
{
    (void)in_sizes; (void)n_in; (void)out_size; (void)ws_size;
    const float* img        = (const float*)d_in[0];
    const float* fromrgb_w  = (const float*)d_in[1];
    const float* fromrgb_b  = (const float*)d_in[2];
    const float* freqs      = (const float*)d_in[3];
    const float* phases     = (const float*)d_in[4];
    const float* hz_outdim  = (const float*)d_in[5];
    const float* vt_outdim  = (const float*)d_in[6];
    const float* gsig       = (const float*)d_in[7];
    const float* lr_w       = (const float*)d_in[8];
    const float* point_w    = (const float*)d_in[9];
    const float* point_b    = (const float*)d_in[10];
    const float* low_filter = (const float*)d_in[11];
    const float* gauss_x    = (const float*)d_in[12];
    const float* fir        = (const float*)d_in[13];

    char* ws = (char*)d_ws;
    u16*   xu   = (u16*)(ws);                      // 262144*512*2  = 256 MiB
    u16*   ypre = (u16*)(ws + 268435456LL);        // 16*256*128*128*2 = 128 MiB
    u16*   wcat = (u16*)(ws + 402653184LL);        // 512*512*2 = 512 KiB
    float* hzvt = (float*)(ws + 403177472LL);      // 2*256*3*4 = 6 KiB
    float* out  = (float*)d_out;

    hipLaunchKernelGGL(prep_kernel, dim3(8706), dim3(256), 0, stream,
                       freqs, phases, hz_outdim, vt_outdim, gsig, low_filter, gauss_x, hzvt,
                       point_w, lr_w, wcat, img, fromrgb_w, fromrgb_b, xu);
    hipLaunchKernelGGL(dw_kernel, dim3(8192), dim3(256), 0, stream,
                       xu, hzvt);
    for (int half = 0; half < 2; half++) {
        hipLaunchKernelGGL(gemm_kernel, dim3(4096), dim3(256), 0, stream,
                           xu, wcat, point_b, ypre, half * 256);
        hipLaunchKernelGGL(fir_kernel, dim3(8192), dim3(256), 0, stream,
                           ypre, fir, out, half * 256);
    }
}